// Round 1
// baseline (445.172 us; speedup 1.0000x reference)
//
#include <hip/hip_runtime.h>

#define NT 65536
#define MD 1024
#define NE 64
#define BK 32

// ---------------------------------------------------------------------------
// Kernel 1: fused gating GEMM + argmax + softmax + me/ce accumulation.
// One block = 64 tokens x 64 experts tile, 256 threads, 4x4 per-thread tile.
// ---------------------------------------------------------------------------
__global__ __launch_bounds__(256) void gate_kernel(
    const float* __restrict__ x, const float* __restrict__ wg,
    float* __restrict__ out, int* __restrict__ idx_ws,
    float* __restrict__ me, float* __restrict__ ce)
{
    // staging: as/bs [BK][64+4] (pad 4 keeps 16B alignment, breaks bank stride)
    __shared__ __align__(16) float smem[2 * BK * 68];
    float (*as)[68] = (float (*)[68])smem;
    float (*bs)[68] = (float (*)[68])(smem + BK * 68);

    const int tid = threadIdx.x;
    const int tx = tid & 15;   // expert quad
    const int ty = tid >> 4;   // token quad
    const int t0 = blockIdx.x * 64;

    float acc[4][4];
#pragma unroll
    for (int i = 0; i < 4; ++i)
#pragma unroll
        for (int j = 0; j < 4; ++j) acc[i][j] = 0.f;

    for (int k0 = 0; k0 < MD; k0 += BK) {
        // stage x tile (64 tok x 32 k) and wg tile (64 exp x 32 k), transposed
#pragma unroll
        for (int l = 0; l < 2; ++l) {
            int flat = tid + l * 256;
            int r = flat >> 3;       // row (token or expert)
            int q = flat & 7;        // float4 index along k
            float4 v = *(const float4*)(x + (size_t)(t0 + r) * MD + k0 + q * 4);
            as[q * 4 + 0][r] = v.x; as[q * 4 + 1][r] = v.y;
            as[q * 4 + 2][r] = v.z; as[q * 4 + 3][r] = v.w;
            float4 w = *(const float4*)(wg + (size_t)r * MD + k0 + q * 4);
            bs[q * 4 + 0][r] = w.x; bs[q * 4 + 1][r] = w.y;
            bs[q * 4 + 2][r] = w.z; bs[q * 4 + 3][r] = w.w;
        }
        __syncthreads();
#pragma unroll
        for (int k = 0; k < BK; ++k) {
            float4 a = *(const float4*)&as[k][ty * 4];
            float4 b = *(const float4*)&bs[k][tx * 4];
            float av[4] = {a.x, a.y, a.z, a.w};
            float bv[4] = {b.x, b.y, b.z, b.w};
#pragma unroll
            for (int i = 0; i < 4; ++i)
#pragma unroll
                for (int j = 0; j < 4; ++j) acc[i][j] += av[i] * bv[j];
        }
        __syncthreads();
    }

    // ---- epilogue: logits tile -> LDS, per-token argmax/softmax ----
    float* lt  = smem;                   // 64 x 65 logits tile
    float* inv = smem + 4160;            // 64 inv-softmax-sums
    int*   hist = (int*)(smem + 4224);   // 64 per-expert counts

#pragma unroll
    for (int i = 0; i < 4; ++i)
#pragma unroll
        for (int j = 0; j < 4; ++j)
            lt[(ty * 4 + i) * 65 + tx * 4 + j] = acc[i][j];
    if (tid < NE) hist[tid] = 0;
    __syncthreads();

    if (tid < 64) {
        const int t = tid;
        float m = -1e30f; int am = 0;
        for (int e = 0; e < NE; ++e) {
            float v = lt[t * 65 + e];
            if (v > m) { m = v; am = e; }   // strict > : first-max like jnp.argmax
        }
        float s = 0.f;
        for (int e = 0; e < NE; ++e) {
            float ev = __expf(lt[t * 65 + e] - m);
            lt[t * 65 + e] = ev;            // keep exp values for me column sums
            s += ev;
        }
        float g = 1.0f / s;                 // gate of argmax = exp(0)/s
        int gt = t0 + t;
        out[1 + gt] = (float)am;            // indices1_s
        out[2 + 2 * NT + gt] = g;           // gates1_s
        idx_ws[gt] = am;
        atomicAdd(&hist[am], 1);
        inv[t] = g;
    }
    __syncthreads();

    if (tid < NE) {
        const int e = tid;
        float s = 0.f;
        for (int t = 0; t < 64; ++t) s += lt[t * 65 + e] * inv[t];
        atomicAdd(&me[e], s);
        atomicAdd(&ce[e], (float)hist[e]);
    }
}

// ---------------------------------------------------------------------------
// Kernel 2: locations1_s. One block per expert; ordered scan over all tokens.
// Each thread owns 16 consecutive tokens per chunk (4096 tokens/chunk).
// ---------------------------------------------------------------------------
__global__ __launch_bounds__(256) void locations_kernel(
    const int* __restrict__ idx, float* __restrict__ out)
{
    const int e = blockIdx.x;
    const int tid = threadIdx.x;
    const int lane = tid & 63;
    const int wave = tid >> 6;
    __shared__ int wpre[4];
    float* out_loc = out + 2 + NT;
    const int4* idx4 = (const int4*)idx;

    int running = 0;
    for (int c = 0; c < NT / 4096; ++c) {
        int base4 = c * 1024 + tid * 4;
        int4 v0 = idx4[base4 + 0];
        int4 v1 = idx4[base4 + 1];
        int4 v2 = idx4[base4 + 2];
        int4 v3 = idx4[base4 + 3];
        int vals[16] = {v0.x, v0.y, v0.z, v0.w, v1.x, v1.y, v1.z, v1.w,
                        v2.x, v2.y, v2.z, v2.w, v3.x, v3.y, v3.z, v3.w};
        unsigned mask = 0;
#pragma unroll
        for (int j = 0; j < 16; ++j)
            if (vals[j] == e) mask |= (1u << j);
        int cnt = __popc(mask);

        // inclusive scan of cnt across the 64-lane wave
        int scan = cnt;
#pragma unroll
        for (int d = 1; d < 64; d <<= 1) {
            int o = __shfl_up(scan, d, 64);
            if (lane >= d) scan += o;
        }
        if (lane == 63) wpre[wave] = scan;
        __syncthreads();
        int wprefix = 0;
#pragma unroll
        for (int w = 0; w < 4; ++w)
            if (w < wave) wprefix += wpre[w];
        int tot = wpre[0] + wpre[1] + wpre[2] + wpre[3];

        int myexcl = running + wprefix + (scan - cnt);
        int r = 0;
#pragma unroll
        for (int j = 0; j < 16; ++j) {
            if (mask & (1u << j)) {
                out_loc[c * 4096 + tid * 16 + j] = (float)(myexcl + r);
                ++r;
            }
        }
        running += tot;
        __syncthreads();
    }
}

// ---------------------------------------------------------------------------
// Kernel 3: l_aux + scalar outputs.
// ---------------------------------------------------------------------------
__global__ void finalize_kernel(const float* __restrict__ me,
                                const float* __restrict__ ce,
                                float* __restrict__ out)
{
    int tid = threadIdx.x;  // 64 threads = 1 wave
    float v = me[tid] * ce[tid];
#pragma unroll
    for (int d = 32; d > 0; d >>= 1) v += __shfl_down(v, d, 64);
    if (tid == 0) {
        out[0] = v * (float)((double)NE / ((double)NT * (double)NT));
        out[1 + NT] = 1024.0f;      // capacity = ceil(N/E) * 1.0
        out[2 + 3 * NT] = 64.0f;    // E
    }
}

extern "C" void kernel_launch(void* const* d_in, const int* in_sizes, int n_in,
                              void* d_out, int out_size, void* d_ws, size_t ws_size,
                              hipStream_t stream)
{
    const float* x  = (const float*)d_in[0];
    const float* wg = (const float*)d_in[1];
    float* out = (float*)d_out;

    int*   idx_ws = (int*)d_ws;                                  // NT ints
    float* me = (float*)((char*)d_ws + (size_t)NT * sizeof(int)); // NE floats
    float* ce = me + NE;                                          // NE floats

    hipMemsetAsync(me, 0, 2 * NE * sizeof(float), stream);
    gate_kernel<<<NT / 64, 256, 0, stream>>>(x, wg, out, idx_ws, me, ce);
    locations_kernel<<<NE, 256, 0, stream>>>(idx_ws, out);
    finalize_kernel<<<1, 64, 0, stream>>>(me, ce, out);
}

// Round 2
// 408.823 us; speedup vs baseline: 1.0889x; 1.0889x over previous
//
#include <hip/hip_runtime.h>

#define NT 65536
#define MD 1024
#define NE 64
#define BK 32
#define NBLK (NT / 64)   // 1024 gate blocks, 64 tokens each

// ---------------------------------------------------------------------------
// Kernel 1: fused gating GEMM + argmax + softmax + rank/hist + me accumulation.
// 64 tokens x 64 experts per block, 256 threads, 4x4 per-thread tile.
// Double-buffered LDS with register prefetch: 1 barrier / K-iteration.
// ---------------------------------------------------------------------------
__global__ __launch_bounds__(256) void gate_kernel(
    const float* __restrict__ x, const float* __restrict__ wg,
    float* __restrict__ out, unsigned* __restrict__ packed_ws,
    int* __restrict__ hist_ws, float* __restrict__ me)
{
    // as[2][BK][68] + bs[2][BK][68]  (pad 68: keeps 16B alignment for b128 reads)
    __shared__ __align__(16) float smem[4 * BK * 68];
    float (*as)[BK][68] = (float (*)[BK][68])smem;
    float (*bs)[BK][68] = (float (*)[BK][68])(smem + 2 * BK * 68);

    const int tid = threadIdx.x;
    const int tx = tid & 15;   // expert quad
    const int ty = tid >> 4;   // token quad
    const int t0 = blockIdx.x * 64;

    // staging assignment: two (row, quad) pairs per thread
    const int r0 = tid >> 3, q0 = tid & 7;
    const int r1 = r0 + 32,  q1 = q0;
    const float* xa0 = x  + (size_t)(t0 + r0) * MD + q0 * 4;
    const float* xa1 = x  + (size_t)(t0 + r1) * MD + q1 * 4;
    const float* wa0 = wg + (size_t)r0 * MD + q0 * 4;
    const float* wa1 = wg + (size_t)r1 * MD + q1 * 4;

    float4 va0 = *(const float4*)(xa0);
    float4 va1 = *(const float4*)(xa1);
    float4 vw0 = *(const float4*)(wa0);
    float4 vw1 = *(const float4*)(wa1);

#define STAGE(buf)                                                      \
    do {                                                                \
        as[buf][q0 * 4 + 0][r0] = va0.x; as[buf][q0 * 4 + 1][r0] = va0.y; \
        as[buf][q0 * 4 + 2][r0] = va0.z; as[buf][q0 * 4 + 3][r0] = va0.w; \
        as[buf][q1 * 4 + 0][r1] = va1.x; as[buf][q1 * 4 + 1][r1] = va1.y; \
        as[buf][q1 * 4 + 2][r1] = va1.z; as[buf][q1 * 4 + 3][r1] = va1.w; \
        bs[buf][q0 * 4 + 0][r0] = vw0.x; bs[buf][q0 * 4 + 1][r0] = vw0.y; \
        bs[buf][q0 * 4 + 2][r0] = vw0.z; bs[buf][q0 * 4 + 3][r0] = vw0.w; \
        bs[buf][q1 * 4 + 0][r1] = vw1.x; bs[buf][q1 * 4 + 1][r1] = vw1.y; \
        bs[buf][q1 * 4 + 2][r1] = vw1.z; bs[buf][q1 * 4 + 3][r1] = vw1.w; \
    } while (0)

    STAGE(0);
    __syncthreads();

    float acc[4][4];
#pragma unroll
    for (int i = 0; i < 4; ++i)
#pragma unroll
        for (int j = 0; j < 4; ++j) acc[i][j] = 0.f;

    for (int it = 0; it < MD / BK; ++it) {
        const int cur = it & 1;
        if (it < MD / BK - 1) {
            const int kn = (it + 1) * BK;
            va0 = *(const float4*)(xa0 + kn);
            va1 = *(const float4*)(xa1 + kn);
            vw0 = *(const float4*)(wa0 + kn);
            vw1 = *(const float4*)(wa1 + kn);
        }
#pragma unroll
        for (int k = 0; k < BK; ++k) {
            float4 a = *(const float4*)&as[cur][k][ty * 4];
            float4 b = *(const float4*)&bs[cur][k][tx * 4];
            float av[4] = {a.x, a.y, a.z, a.w};
            float bv[4] = {b.x, b.y, b.z, b.w};
#pragma unroll
            for (int i = 0; i < 4; ++i)
#pragma unroll
                for (int j = 0; j < 4; ++j) acc[i][j] += av[i] * bv[j];
        }
        if (it < MD / BK - 1) {
            const int nb = cur ^ 1;
            STAGE(nb);
        }
        __syncthreads();
    }

    // ---- epilogue ----
    float* lt  = smem;                   // 64 x 65 logits tile
    float* inv = smem + 4160;            // 64 softmax reciprocals

#pragma unroll
    for (int i = 0; i < 4; ++i)
#pragma unroll
        for (int j = 0; j < 4; ++j)
            lt[(ty * 4 + i) * 65 + tx * 4 + j] = acc[i][j];
    __syncthreads();

    if (tid < 64) {
        const int t = tid;
        float m = -1e30f; int am = 0;
        for (int e = 0; e < NE; ++e) {
            float v = lt[t * 65 + e];
            if (v > m) { m = v; am = e; }   // strict > : first-max like jnp.argmax
        }
        float s = 0.f;
        for (int e = 0; e < NE; ++e) {
            float ev = __expf(lt[t * 65 + e] - m);
            lt[t * 65 + e] = ev;
            s += ev;
        }
        float g = 1.0f / s;
        const int gt = t0 + t;
        out[1 + gt] = (float)am;            // indices1_s
        out[2 + 2 * NT + gt] = g;           // gates1_s
        inv[t] = g;

        // rank within block (token order == lane order) + per-expert count
        const unsigned long long below = (1ull << t) - 1ull;
        int rank = 0, mycnt = 0;
        for (int e = 0; e < NE; ++e) {
            unsigned long long msk = __ballot(am == e);
            if (t == e)  mycnt = (int)__popcll(msk);
            if (am == e) rank  = (int)__popcll(msk & below);
        }
        packed_ws[gt] = (unsigned)am | ((unsigned)rank << 8);
        hist_ws[blockIdx.x * NE + t] = mycnt;   // lane t reports expert t's count
    }
    __syncthreads();

    if (tid < NE) {
        const int e = tid;
        float s = 0.f;
        for (int t = 0; t < 64; ++t) s += lt[t * 65 + e] * inv[t];
        atomicAdd(&me[e], s);
    }
}

// ---------------------------------------------------------------------------
// Kernel 2: per-expert exclusive scan over the 1024 block histograms
// (in-place: hist_ws becomes block offsets). Also emits ce[e] = total.
// ---------------------------------------------------------------------------
__global__ __launch_bounds__(256) void scan_kernel(
    int* __restrict__ hist_ws, float* __restrict__ ce)
{
    const int e = blockIdx.x;
    const int tid = threadIdx.x;
    const int lane = tid & 63, wave = tid >> 6;
    __shared__ int wtot[4];

    int h[4];
#pragma unroll
    for (int j = 0; j < 4; ++j) h[j] = hist_ws[(tid * 4 + j) * NE + e];
    int s = h[0] + h[1] + h[2] + h[3];

    int scan = s;
#pragma unroll
    for (int d = 1; d < 64; d <<= 1) {
        int o = __shfl_up(scan, d, 64);
        if (lane >= d) scan += o;
    }
    if (lane == 63) wtot[wave] = scan;
    __syncthreads();
    int wpre = 0;
#pragma unroll
    for (int w = 0; w < 4; ++w)
        if (w < wave) wpre += wtot[w];

    int run = wpre + scan - s;   // exclusive prefix for this thread's 4 blocks
#pragma unroll
    for (int j = 0; j < 4; ++j) {
        hist_ws[(tid * 4 + j) * NE + e] = run;
        run += h[j];
    }
    if (tid == 255) ce[e] = (float)run;  // total tokens routed to expert e
}

// ---------------------------------------------------------------------------
// Kernel 3: locations1_s[i] = offs[block][expert] + rank_within_block.
// ---------------------------------------------------------------------------
__global__ __launch_bounds__(256) void emit_kernel(
    const unsigned* __restrict__ packed_ws, const int* __restrict__ offs_ws,
    float* __restrict__ out)
{
    const int i = blockIdx.x * 256 + threadIdx.x;
    const unsigned p = packed_ws[i];
    const int am = (int)(p & 63u);
    const int rank = (int)(p >> 8);
    const int b = i >> 6;
    out[2 + NT + i] = (float)(offs_ws[b * NE + am] + rank);
}

// ---------------------------------------------------------------------------
// Kernel 4: l_aux + scalar outputs.
// ---------------------------------------------------------------------------
__global__ void finalize_kernel(const float* __restrict__ me,
                                const float* __restrict__ ce,
                                float* __restrict__ out)
{
    int tid = threadIdx.x;  // 64 threads = 1 wave
    float v = me[tid] * ce[tid];
#pragma unroll
    for (int d = 32; d > 0; d >>= 1) v += __shfl_down(v, d, 64);
    if (tid == 0) {
        out[0] = v * (float)((double)NE / ((double)NT * (double)NT));
        out[1 + NT] = 1024.0f;      // capacity = ceil(N/E) * 1.0
        out[2 + 3 * NT] = 64.0f;    // E
    }
}

extern "C" void kernel_launch(void* const* d_in, const int* in_sizes, int n_in,
                              void* d_out, int out_size, void* d_ws, size_t ws_size,
                              hipStream_t stream)
{
    const float* x  = (const float*)d_in[0];
    const float* wg = (const float*)d_in[1];
    float* out = (float*)d_out;

    unsigned* packed_ws = (unsigned*)d_ws;                         // NT uints
    int* hist_ws = (int*)((char*)d_ws + (size_t)NT * 4);           // NBLK*NE ints
    float* me = (float*)((char*)d_ws + (size_t)NT * 4 + (size_t)NBLK * NE * 4);
    float* ce = me + NE;

    hipMemsetAsync(me, 0, NE * sizeof(float), stream);
    gate_kernel<<<NBLK, 256, 0, stream>>>(x, wg, out, packed_ws, hist_ws, me);
    scan_kernel<<<NE, 256, 0, stream>>>(hist_ws, ce);
    emit_kernel<<<NT / 256, 256, 0, stream>>>(packed_ws, hist_ws, out);
    finalize_kernel<<<1, 64, 0, stream>>>(me, ce, out);
}